// Round 10
// baseline (173.552 us; speedup 1.0000x reference)
//
#include <hip/hip_runtime.h>
#include <hip/hip_bf16.h>

typedef __bf16 bf16_t;
typedef __bf16 bf16x8 __attribute__((ext_vector_type(8)));
typedef __bf16 bf16x4 __attribute__((ext_vector_type(4)));
typedef short  s16x4  __attribute__((ext_vector_type(4)));
typedef float  f32x4  __attribute__((ext_vector_type(4)));

#define B_DIM 8
#define C_DIM 512
#define T_DIM 1024
#define NH 8
#define HD 64

// v_mfma_f32_16x16x16_bf16: A/B = 4 bf16 (k=quad*4+j, m/n=l15), C row=quad*4+r col=l15.
__device__ __forceinline__ f32x4 mfma16_bf16(bf16x4 a, bf16x4 b, f32x4 c) {
    return __builtin_amdgcn_mfma_f32_16x16x16bf16_1k(
        __builtin_bit_cast(s16x4, a), __builtin_bit_cast(s16x4, b), c, 0, 0, 0);
}

// ---------------------------------------------------------------------------
// Kernel 0: one-time weight conversion fp32 -> bf16.
// ---------------------------------------------------------------------------
__global__ __launch_bounds__(256) void prep_w(const float* __restrict__ w1,
                                              const float* __restrict__ w2,
                                              bf16_t* __restrict__ o1,
                                              bf16_t* __restrict__ o2)
{
    int tid = blockIdx.x * 256 + threadIdx.x;
    for (int p = 0; p < 4; ++p) {
        int q = tid + p * 65536;
        const f32x4* src;
        bf16x4* dst;
        int qq;
        if (q < 196608) { src = (const f32x4*)w1; dst = (bf16x4*)o1; qq = q; }
        else            { src = (const f32x4*)w2; dst = (bf16x4*)o2; qq = q - 196608; }
        f32x4 f = src[qq];
        bf16x4 h;
        for (int j = 0; j < 4; ++j) h[j] = (bf16_t)f[j];
        dst[qq] = h;
    }
}

// ---------------------------------------------------------------------------
// Kernel 1: GroupNorm.  x (b,c,t) fp32 -> n_t (b,t,c) bf16.  (unchanged)
// ---------------------------------------------------------------------------
__global__ __launch_bounds__(256) void gn_kernel(const float* __restrict__ x,
                                                 const float* __restrict__ gw,
                                                 const float* __restrict__ gb,
                                                 bf16_t* __restrict__ n_t)
{
    __shared__ bf16_t sX[16384];
    __shared__ float sred[8];
    int tid = threadIdx.x;
    int bb  = blockIdx.x >> 5;
    int g   = blockIdx.x & 31;
    const f32x4* xg4 = reinterpret_cast<const f32x4*>(x + (size_t)(bb * C_DIM + g * 16) * T_DIM);

    float s = 0.f, sq = 0.f;
    for (int i = 0; i < 16; ++i) {
        int v = tid + i * 256;
        f32x4 f = xg4[v];
        bf16x4 h;
        for (int j = 0; j < 4; ++j) {
            s += f[j]; sq += f[j] * f[j];
            h[j] = (bf16_t)f[j];
        }
        *reinterpret_cast<bf16x4*>(sX + v * 4) = h;
    }
    for (int off = 1; off < 64; off <<= 1) {
        s  += __shfl_xor(s, off);
        sq += __shfl_xor(sq, off);
    }
    int wv = tid >> 6;
    if ((tid & 63) == 0) { sred[wv * 2] = s; sred[wv * 2 + 1] = sq; }
    __syncthreads();
    s  = sred[0] + sred[2] + sred[4] + sred[6];
    sq = sred[1] + sred[3] + sred[5] + sred[7];
    float mean = s * (1.f / 16384.f);
    float var  = sq * (1.f / 16384.f) - mean * mean;
    float rs   = rsqrtf(var + 1e-5f);

    int hf = tid & 1;
    float aa[8], bbias[8];
    for (int j = 0; j < 8; ++j) {
        int c = hf * 8 + j;
        float av = gw[g * 16 + c] * rs;
        aa[j] = av;
        bbias[j] = gb[g * 16 + c] - mean * av;
    }
    bf16_t* ob = n_t + (size_t)bb * T_DIM * C_DIM + g * 16 + hf * 8;
    for (int p = 0; p < 8; ++p) {
        int t = (tid >> 1) + p * 128;
        bf16x8 o;
        for (int j = 0; j < 8; ++j) {
            float xv = (float)sX[(hf * 8 + j) * 1024 + t];
            o[j] = (bf16_t)(xv * aa[j] + bbias[j]);
        }
        *reinterpret_cast<bf16x8*>(ob + (size_t)t * C_DIM) = o;
    }
}

// ---------------------------------------------------------------------------
// Kernel 2: QKV GEMM, round 10: 128x128 tile (m93-class), BK=64.
// 4 waves in 2x2; each wave owns 64x64 (4x4 MFMA tiles, 64-VGPR acc).
// Epilogue: the block's two 64-row (head,type) chunks are transposed through
// LDS sequentially -- (t,c) for q/k, (c,t) for v -- then stored with b128.
// ---------------------------------------------------------------------------
__global__ __launch_bounds__(256) void qkv_gemm_kernel(
    const bf16_t* __restrict__ wqb, const float* __restrict__ bq,
    const bf16_t* __restrict__ n_t, bf16_t* __restrict__ qkv)
{
    __shared__ bf16_t sA[128 * 72];
    __shared__ bf16_t sB[128 * 72];
    int tid = threadIdx.x;
    int w = tid >> 6, lane = tid & 63, quad = lane >> 4, l15 = lane & 15;
    int bx = blockIdx.x;          // 0..11 -> o rows [bx*128, bx*128+128)
    int t0 = blockIdx.y * 128;
    int bb = blockIdx.z;
    int o0 = bx * 128;
    const bf16_t* Ab = wqb + (size_t)o0 * C_DIM;
    const bf16_t* Bb = n_t + ((size_t)bb * T_DIM + t0) * C_DIM;

    f32x4 acc[4][4];
    for (int mt = 0; mt < 4; ++mt)
        for (int nt = 0; nt < 4; ++nt)
            acc[mt][nt] = f32x4{0.f, 0.f, 0.f, 0.f};
    int mw0 = (w >> 1) * 64;
    int nw0 = (w & 1) * 64;

    for (int k0 = 0; k0 < C_DIM; k0 += 64) {
        for (int i = 0; i < 4; ++i) {
            int v = tid + i * 256;        // 0..1023
            int row = v >> 3, c8 = v & 7;
            *reinterpret_cast<bf16x8*>(sA + row * 72 + c8 * 8) =
                *reinterpret_cast<const bf16x8*>(Ab + (size_t)row * C_DIM + k0 + c8 * 8);
            *reinterpret_cast<bf16x8*>(sB + row * 72 + c8 * 8) =
                *reinterpret_cast<const bf16x8*>(Bb + (size_t)row * C_DIM + k0 + c8 * 8);
        }
        __syncthreads();
        for (int kk = 0; kk < 2; ++kk) {
            bf16x8 af[4], bfr[4];
            for (int mt = 0; mt < 4; ++mt)
                af[mt] = *reinterpret_cast<const bf16x8*>(sA + (mw0 + mt * 16 + l15) * 72 + kk * 32 + quad * 8);
            for (int nt = 0; nt < 4; ++nt)
                bfr[nt] = *reinterpret_cast<const bf16x8*>(sB + (nw0 + nt * 16 + l15) * 72 + kk * 32 + quad * 8);
            for (int mt = 0; mt < 4; ++mt)
                for (int nt = 0; nt < 4; ++nt)
                    acc[mt][nt] = __builtin_amdgcn_mfma_f32_16x16x32_bf16(af[mt], bfr[nt], acc[mt][nt], 0, 0, 0);
        }
        __syncthreads();
    }

    // ---- epilogue: two 64-row chunks, each its own (head,type) layout ----
    for (int mh = 0; mh < 2; ++mh) {
        int chunk = 2 * bx + mh;          // 0..23 = h*3 + type
        int h = chunk / 3, type = chunk % 3;
        size_t base = ((size_t)(bb * NH + h) * 3 + type) * (64 * 1024);

        __syncthreads();                  // previous store phase done
        if ((w >> 1) == mh) {             // the 2 waves owning these rows
            if (type < 2) {
                for (int mt = 0; mt < 4; ++mt)
                    for (int nt = 0; nt < 4; ++nt)
                        for (int r = 0; r < 4; ++r) {
                            int mw = mt * 16 + quad * 4 + r;          // 0..63 local
                            int tl = nw0 + nt * 16 + l15;             // 0..127
                            float v = acc[mt][nt][r] + bq[o0 + mh * 64 + mw];
                            sB[tl * 72 + mw] = (bf16_t)v;
                        }
            } else {
                for (int mt = 0; mt < 4; ++mt)
                    for (int nt = 0; nt < 4; ++nt)
                        for (int r = 0; r < 4; ++r) {
                            int mw = mt * 16 + quad * 4 + r;
                            int tl = nw0 + nt * 16 + l15;
                            float v = acc[mt][nt][r] + bq[o0 + mh * 64 + mw];
                            sB[mw * 136 + tl] = (bf16_t)v;
                        }
            }
        }
        __syncthreads();
        if (type < 2) {
            // store (t,c): 128 x 64
            for (int i = 0; i < 4; ++i) {
                int v = tid + i * 256;            // 0..1023
                int tl = v >> 3, c8 = v & 7;
                bf16x8 d = *reinterpret_cast<const bf16x8*>(sB + tl * 72 + c8 * 8);
                *reinterpret_cast<bf16x8*>(qkv + base + (size_t)(t0 + tl) * 64 + c8 * 8) = d;
            }
        } else {
            // store (c,t): 64 x 128
            for (int i = 0; i < 4; ++i) {
                int v = tid + i * 256;
                int cc = v >> 4, t8 = (v & 15) * 8;
                bf16x8 d = *reinterpret_cast<const bf16x8*>(sB + cc * 136 + t8);
                *reinterpret_cast<bf16x8*>(qkv + base + (size_t)cc * 1024 + t0 + t8) = d;
            }
        }
    }
}

// ---------------------------------------------------------------------------
// Kernel 3: flash attention (unchanged from round 9).
// ---------------------------------------------------------------------------
__global__ __launch_bounds__(256, 6) void attn_kernel(const bf16_t* __restrict__ qkv,
                                                      bf16_t* __restrict__ net_t)
{
    __shared__ bf16_t sK[64 * 72];
    __shared__ bf16_t sV[64 * 72];      // (c=64 rows, s=64 cols)
    int tid = threadIdx.x;
    int w = tid >> 6, lane = tid & 63, quad = lane >> 4, l15 = lane & 15;
    int bh = blockIdx.x;
    int qt = blockIdx.y;
    size_t qb = (size_t)bh * 3 * 65536;
    const bf16_t* Qg = qkv + qb + (size_t)qt * 4096;
    const bf16_t* Kg = qkv + qb + 65536;
    const bf16_t* Vg = qkv + qb + 2 * 65536;
    const float K2 = 0.125f * 1.44269504088896f;   // scale^2 * log2(e)

    bf16x8 qf[2];
    for (int kk = 0; kk < 2; ++kk)
        qf[kk] = *reinterpret_cast<const bf16x8*>(Qg + (size_t)(w * 16 + l15) * 64 + kk * 32 + quad * 8);

    bf16x8 kreg[2], vreg[2];
    for (int i = 0; i < 2; ++i) {
        int v = tid + i * 256;
        kreg[i] = *reinterpret_cast<const bf16x8*>(Kg + (size_t)(v >> 3) * 64 + (v & 7) * 8);
        vreg[i] = *reinterpret_cast<const bf16x8*>(Vg + (size_t)(v >> 3) * 1024 + (v & 7) * 8);
    }

    f32x4 O[4];   // O^T: [ct] rows c=ct*16+quad*4+r, col t=l15
    for (int i = 0; i < 4; ++i) O[i] = f32x4{0.f, 0.f, 0.f, 0.f};
    float lsum = 0.f;

    for (int st = 0; st < 16; ++st) {
        __syncthreads();
        for (int i = 0; i < 2; ++i) {
            int v = tid + i * 256;
            *reinterpret_cast<bf16x8*>(sK + (v >> 3) * 72 + (v & 7) * 8) = kreg[i];
            *reinterpret_cast<bf16x8*>(sV + (v >> 3) * 72 + (v & 7) * 8) = vreg[i];
        }
        __syncthreads();
        if (st < 15) {
            int s0n = (st + 1) * 64;
            for (int i = 0; i < 2; ++i) {
                int v = tid + i * 256;
                kreg[i] = *reinterpret_cast<const bf16x8*>(Kg + (size_t)(s0n + (v >> 3)) * 64 + (v & 7) * 8);
                vreg[i] = *reinterpret_cast<const bf16x8*>(Vg + (size_t)(v >> 3) * 1024 + s0n + (v & 7) * 8);
            }
        }

        for (int mt = 0; mt < 4; ++mt) {
            f32x4 S = f32x4{0.f, 0.f, 0.f, 0.f};
            for (int kk = 0; kk < 2; ++kk) {
                bf16x8 kf = *reinterpret_cast<const bf16x8*>(sK + (mt * 16 + l15) * 72 + kk * 32 + quad * 8);
                S = __builtin_amdgcn_mfma_f32_16x16x32_bf16(kf, qf[kk], S, 0, 0, 0);
            }
            bf16x4 pf;
            for (int r = 0; r < 4; ++r) {
                float p = exp2f(S[r] * K2);
                lsum += p;
                pf[r] = (bf16_t)p;
            }
            for (int ct = 0; ct < 4; ++ct) {
                bf16x4 vf = *reinterpret_cast<const bf16x4*>(sV + (ct * 16 + l15) * 72 + mt * 16 + quad * 4);
                O[ct] = mfma16_bf16(vf, pf, O[ct]);
            }
        }
    }

    lsum += __shfl_xor(lsum, 16);
    lsum += __shfl_xor(lsum, 32);
    float inv = 1.f / lsum;

    int bb = bh >> 3, h = bh & 7;
    int t = qt * 64 + w * 16 + l15;
    bf16_t* orow = net_t + ((size_t)bb * T_DIM + t) * C_DIM + h * 64;
    for (int ct = 0; ct < 4; ++ct) {
        bf16x4 o4;
        for (int r = 0; r < 4; ++r) o4[r] = (bf16_t)(O[ct][r] * inv);
        *reinterpret_cast<bf16x4*>(orow + ct * 16 + quad * 4) = o4;
    }
}

// ---------------------------------------------------------------------------
// Kernel 4: out GEMM + bias + residual (unchanged from round 6).
// ---------------------------------------------------------------------------
__global__ __launch_bounds__(256) void out_gemm_kernel(
    const bf16_t* __restrict__ wob, const float* __restrict__ bo,
    const bf16_t* __restrict__ net_t, const float* __restrict__ x,
    float* __restrict__ out)
{
    __shared__ bf16_t sA[64 * 72];
    __shared__ bf16_t sB[128 * 72];
    int tid = threadIdx.x;
    int w = tid >> 6, lane = tid & 63, quad = lane >> 4, l15 = lane & 15;
    int o0 = blockIdx.x * 64;
    int t0 = blockIdx.y * 128;
    int bb = blockIdx.z;
    const bf16_t* Ab = wob + (size_t)o0 * C_DIM;
    const bf16_t* Bb = net_t + ((size_t)bb * T_DIM + t0) * C_DIM;

    f32x4 acc[2][4];
    for (int mt = 0; mt < 2; ++mt)
        for (int nt = 0; nt < 4; ++nt)
            acc[mt][nt] = f32x4{0.f, 0.f, 0.f, 0.f};
    int mw0 = (w >> 1) * 32;
    int nw0 = (w & 1) * 64;

    for (int k0 = 0; k0 < C_DIM; k0 += 64) {
        for (int i = 0; i < 2; ++i) {
            int v = tid + i * 256;
            int row = v >> 3, c8 = v & 7;
            *reinterpret_cast<bf16x8*>(sA + row * 72 + c8 * 8) =
                *reinterpret_cast<const bf16x8*>(Ab + (size_t)row * C_DIM + k0 + c8 * 8);
        }
        for (int i = 0; i < 4; ++i) {
            int v = tid + i * 256;
            int row = v >> 3, c8 = v & 7;
            *reinterpret_cast<bf16x8*>(sB + row * 72 + c8 * 8) =
                *reinterpret_cast<const bf16x8*>(Bb + (size_t)row * C_DIM + k0 + c8 * 8);
        }
        __syncthreads();
        for (int kk = 0; kk < 2; ++kk) {
            bf16x8 af[2], bfr[4];
            for (int mt = 0; mt < 2; ++mt)
                af[mt] = *reinterpret_cast<const bf16x8*>(sA + (mw0 + mt * 16 + l15) * 72 + kk * 32 + quad * 8);
            for (int nt = 0; nt < 4; ++nt)
                bfr[nt] = *reinterpret_cast<const bf16x8*>(sB + (nw0 + nt * 16 + l15) * 72 + kk * 32 + quad * 8);
            for (int mt = 0; mt < 2; ++mt)
                for (int nt = 0; nt < 4; ++nt)
                    acc[mt][nt] = __builtin_amdgcn_mfma_f32_16x16x32_bf16(af[mt], bfr[nt], acc[mt][nt], 0, 0, 0);
        }
        __syncthreads();
    }

    for (int mt = 0; mt < 2; ++mt)
        for (int nt = 0; nt < 4; ++nt)
            for (int r = 0; r < 4; ++r) {
                int o = o0 + mw0 + mt * 16 + quad * 4 + r;
                int t = t0 + nw0 + nt * 16 + l15;
                size_t idx = ((size_t)bb * C_DIM + o) * T_DIM + t;
                out[idx] = acc[mt][nt][r] + bo[o] + x[idx];
            }
}

// ---------------------------------------------------------------------------
extern "C" void kernel_launch(void* const* d_in, const int* in_sizes, int n_in,
                              void* d_out, int out_size, void* d_ws, size_t ws_size,
                              hipStream_t stream)
{
    const float* x     = (const float*)d_in[0];
    const float* gn_w  = (const float*)d_in[1];
    const float* gn_b  = (const float*)d_in[2];
    const float* qkv_w = (const float*)d_in[3];
    const float* qkv_b = (const float*)d_in[4];
    const float* out_w = (const float*)d_in[5];
    const float* out_b = (const float*)d_in[6];
    float* out = (float*)d_out;

    // ws layout (bf16): n_t 8MB | qkv 24MB | net_t 8MB | wqb 1.5MB | wob 0.5MB
    char* ws = (char*)d_ws;
    bf16_t* n_t   = (bf16_t*)(ws);
    bf16_t* qkv   = (bf16_t*)(ws + 8388608);
    bf16_t* net_t = (bf16_t*)(ws + 33554432);
    bf16_t* wqb   = (bf16_t*)(ws + 41943040);
    bf16_t* wob   = (bf16_t*)(ws + 41943040 + 1572864);

    prep_w<<<dim3(256), 256, 0, stream>>>(qkv_w, out_w, wqb, wob);
    gn_kernel<<<dim3(256), 256, 0, stream>>>(x, gn_w, gn_b, n_t);
    qkv_gemm_kernel<<<dim3(12, 8, 8), 256, 0, stream>>>(wqb, qkv_b, n_t, qkv);
    attn_kernel<<<dim3(64, 16), 256, 0, stream>>>(qkv, net_t);
    out_gemm_kernel<<<dim3(8, 8, 8), 256, 0, stream>>>(wob, out_b, net_t, x, out);
}

// Round 11
// 170.161 us; speedup vs baseline: 1.0199x; 1.0199x over previous
//
#include <hip/hip_runtime.h>
#include <hip/hip_bf16.h>

typedef __bf16 bf16_t;
typedef __bf16 bf16x8 __attribute__((ext_vector_type(8)));
typedef __bf16 bf16x4 __attribute__((ext_vector_type(4)));
typedef short  s16x4  __attribute__((ext_vector_type(4)));
typedef float  f32x4  __attribute__((ext_vector_type(4)));

#define B_DIM 8
#define C_DIM 512
#define T_DIM 1024
#define NH 8
#define HD 64

// v_mfma_f32_16x16x16_bf16: A/B = 4 bf16 (k=quad*4+j, m/n=l15), C row=quad*4+r col=l15.
__device__ __forceinline__ f32x4 mfma16_bf16(bf16x4 a, bf16x4 b, f32x4 c) {
    return __builtin_amdgcn_mfma_f32_16x16x16bf16_1k(
        __builtin_bit_cast(s16x4, a), __builtin_bit_cast(s16x4, b), c, 0, 0, 0);
}

// ---------------------------------------------------------------------------
// Kernel 0: one-time weight conversion fp32 -> bf16.
// ---------------------------------------------------------------------------
__global__ __launch_bounds__(256) void prep_w(const float* __restrict__ w1,
                                              const float* __restrict__ w2,
                                              bf16_t* __restrict__ o1,
                                              bf16_t* __restrict__ o2)
{
    int tid = blockIdx.x * 256 + threadIdx.x;
    for (int p = 0; p < 4; ++p) {
        int q = tid + p * 65536;
        const f32x4* src;
        bf16x4* dst;
        int qq;
        if (q < 196608) { src = (const f32x4*)w1; dst = (bf16x4*)o1; qq = q; }
        else            { src = (const f32x4*)w2; dst = (bf16x4*)o2; qq = q - 196608; }
        f32x4 f = src[qq];
        bf16x4 h;
        for (int j = 0; j < 4; ++j) h[j] = (bf16_t)f[j];
        dst[qq] = h;
    }
}

// ---------------------------------------------------------------------------
// Kernel 1: GroupNorm.  x (b,c,t) fp32 -> n_t (b,t,c) bf16.  (unchanged)
// ---------------------------------------------------------------------------
__global__ __launch_bounds__(256) void gn_kernel(const float* __restrict__ x,
                                                 const float* __restrict__ gw,
                                                 const float* __restrict__ gb,
                                                 bf16_t* __restrict__ n_t)
{
    __shared__ bf16_t sX[16384];
    __shared__ float sred[8];
    int tid = threadIdx.x;
    int bb  = blockIdx.x >> 5;
    int g   = blockIdx.x & 31;
    const f32x4* xg4 = reinterpret_cast<const f32x4*>(x + (size_t)(bb * C_DIM + g * 16) * T_DIM);

    float s = 0.f, sq = 0.f;
    for (int i = 0; i < 16; ++i) {
        int v = tid + i * 256;
        f32x4 f = xg4[v];
        bf16x4 h;
        for (int j = 0; j < 4; ++j) {
            s += f[j]; sq += f[j] * f[j];
            h[j] = (bf16_t)f[j];
        }
        *reinterpret_cast<bf16x4*>(sX + v * 4) = h;
    }
    for (int off = 1; off < 64; off <<= 1) {
        s  += __shfl_xor(s, off);
        sq += __shfl_xor(sq, off);
    }
    int wv = tid >> 6;
    if ((tid & 63) == 0) { sred[wv * 2] = s; sred[wv * 2 + 1] = sq; }
    __syncthreads();
    s  = sred[0] + sred[2] + sred[4] + sred[6];
    sq = sred[1] + sred[3] + sred[5] + sred[7];
    float mean = s * (1.f / 16384.f);
    float var  = sq * (1.f / 16384.f) - mean * mean;
    float rs   = rsqrtf(var + 1e-5f);

    int hf = tid & 1;
    float aa[8], bbias[8];
    for (int j = 0; j < 8; ++j) {
        int c = hf * 8 + j;
        float av = gw[g * 16 + c] * rs;
        aa[j] = av;
        bbias[j] = gb[g * 16 + c] - mean * av;
    }
    bf16_t* ob = n_t + (size_t)bb * T_DIM * C_DIM + g * 16 + hf * 8;
    for (int p = 0; p < 8; ++p) {
        int t = (tid >> 1) + p * 128;
        bf16x8 o;
        for (int j = 0; j < 8; ++j) {
            float xv = (float)sX[(hf * 8 + j) * 1024 + t];
            o[j] = (bf16_t)(xv * aa[j] + bbias[j]);
        }
        *reinterpret_cast<bf16x8*>(ob + (size_t)t * C_DIM) = o;
    }
}

// ---------------------------------------------------------------------------
// Kernel 2: QKV GEMM (reverted to round 9: 64x128 tile, grid (24,8,8)).
// ---------------------------------------------------------------------------
__global__ __launch_bounds__(256) void qkv_gemm_kernel(
    const bf16_t* __restrict__ wqb, const float* __restrict__ bq,
    const bf16_t* __restrict__ n_t, bf16_t* __restrict__ qkv)
{
    __shared__ bf16_t sA[64 * 72];
    __shared__ bf16_t sB[128 * 72];
    int tid = threadIdx.x;
    int w = tid >> 6, lane = tid & 63, quad = lane >> 4, l15 = lane & 15;
    int bx = blockIdx.x;          // 0..23  (= h*3 + type)
    int t0 = blockIdx.y * 128;
    int bb = blockIdx.z;
    int o0 = bx * 64;
    const bf16_t* Ab = wqb + (size_t)o0 * C_DIM;
    const bf16_t* Bb = n_t + ((size_t)bb * T_DIM + t0) * C_DIM;

    f32x4 acc[2][4];
    for (int mt = 0; mt < 2; ++mt)
        for (int nt = 0; nt < 4; ++nt)
            acc[mt][nt] = f32x4{0.f, 0.f, 0.f, 0.f};
    int mw0 = (w >> 1) * 32;
    int nw0 = (w & 1) * 64;

    for (int k0 = 0; k0 < C_DIM; k0 += 64) {
        for (int i = 0; i < 2; ++i) {
            int v = tid + i * 256;
            int row = v >> 3, c8 = v & 7;
            *reinterpret_cast<bf16x8*>(sA + row * 72 + c8 * 8) =
                *reinterpret_cast<const bf16x8*>(Ab + (size_t)row * C_DIM + k0 + c8 * 8);
        }
        for (int i = 0; i < 4; ++i) {
            int v = tid + i * 256;
            int row = v >> 3, c8 = v & 7;
            *reinterpret_cast<bf16x8*>(sB + row * 72 + c8 * 8) =
                *reinterpret_cast<const bf16x8*>(Bb + (size_t)row * C_DIM + k0 + c8 * 8);
        }
        __syncthreads();
        for (int kk = 0; kk < 2; ++kk) {
            bf16x8 af[2], bfr[4];
            for (int mt = 0; mt < 2; ++mt)
                af[mt] = *reinterpret_cast<const bf16x8*>(sA + (mw0 + mt * 16 + l15) * 72 + kk * 32 + quad * 8);
            for (int nt = 0; nt < 4; ++nt)
                bfr[nt] = *reinterpret_cast<const bf16x8*>(sB + (nw0 + nt * 16 + l15) * 72 + kk * 32 + quad * 8);
            for (int mt = 0; mt < 2; ++mt)
                for (int nt = 0; nt < 4; ++nt)
                    acc[mt][nt] = __builtin_amdgcn_mfma_f32_16x16x32_bf16(af[mt], bfr[nt], acc[mt][nt], 0, 0, 0);
        }
        __syncthreads();
    }

    int h = bx / 3, type = bx % 3;
    size_t base = ((size_t)(bb * NH + h) * 3 + type) * (64 * 1024);

    if (type < 2) {
        for (int mt = 0; mt < 2; ++mt)
            for (int nt = 0; nt < 4; ++nt)
                for (int r = 0; r < 4; ++r) {
                    int mw = mw0 + mt * 16 + quad * 4 + r;
                    int tl = nw0 + nt * 16 + l15;
                    float v = acc[mt][nt][r] + bq[o0 + mw];
                    sB[tl * 72 + mw] = (bf16_t)v;
                }
        __syncthreads();
        for (int i = 0; i < 4; ++i) {
            int v = tid + i * 256;
            int tl = v >> 3, c8 = v & 7;
            bf16x8 d = *reinterpret_cast<const bf16x8*>(sB + tl * 72 + c8 * 8);
            *reinterpret_cast<bf16x8*>(qkv + base + (size_t)(t0 + tl) * 64 + c8 * 8) = d;
        }
    } else {
        for (int mt = 0; mt < 2; ++mt)
            for (int nt = 0; nt < 4; ++nt)
                for (int r = 0; r < 4; ++r) {
                    int mw = mw0 + mt * 16 + quad * 4 + r;
                    int tl = nw0 + nt * 16 + l15;
                    float v = acc[mt][nt][r] + bq[o0 + mw];
                    sB[mw * 136 + tl] = (bf16_t)v;
                }
        __syncthreads();
        for (int i = 0; i < 4; ++i) {
            int v = tid + i * 256;
            int cc = v >> 4, t8 = (v & 15) * 8;
            bf16x8 d = *reinterpret_cast<const bf16x8*>(sB + cc * 136 + t8);
            *reinterpret_cast<bf16x8*>(qkv + base + (size_t)cc * 1024 + t0 + t8) = d;
        }
    }
}

// ---------------------------------------------------------------------------
// Kernel 3: flash attention, round 11 -- wave-disjoint LDS reads.
// Each wave owns a 16-wide s-slice and ALL 64 q-rows (Q in registers):
//   S^T[w's s][q] = K_w . Q^T      (kf: 2 b128/tile, wave-disjoint)
//   P in registers (K=16 operand layout), lsum per (nt) q-group
//   O^T[c][q] += V[c][w's s].P^T   (vf: 4 b64/tile, reused over nt)
// LDS read bytes/wave-tile: 64 B/lane vs 256 in R9.  End: cross-wave
// reduction of bf16 partial O + lsum through aliased LDS scratch.
// ---------------------------------------------------------------------------
__global__ __launch_bounds__(256) void attn_kernel(const bf16_t* __restrict__ qkv,
                                                   bf16_t* __restrict__ net_t)
{
    __shared__ __align__(16) char smem[37888];
    bf16_t* sK = (bf16_t*)smem;            // 64 x 72  (s rows, c cols)
    bf16_t* sV = (bf16_t*)(smem + 9216);   // 64 x 72  (c rows, s cols)
    bf16_t* sO = (bf16_t*)smem;            // [4 waves][64 q][72 c] bf16 partials
    float*  sL = (float*)(smem + 36864);   // [4 waves][64 q]

    int tid = threadIdx.x;
    int w = tid >> 6, lane = tid & 63, quad = lane >> 4, l15 = lane & 15;
    int bh = blockIdx.x;
    int qt = blockIdx.y;
    size_t qb = (size_t)bh * 3 * 65536;
    const bf16_t* Qg = qkv + qb + (size_t)qt * 4096;
    const bf16_t* Kg = qkv + qb + 65536;
    const bf16_t* Vg = qkv + qb + 2 * 65536;
    const float K2 = 0.125f * 1.44269504088896f;   // scale^2 * log2(e)

    // Q B-fragments for ALL 64 q rows (4 nt groups), k = c.  32 VGPRs.
    bf16x8 qf[4][2];
    for (int nt = 0; nt < 4; ++nt)
        for (int kk = 0; kk < 2; ++kk)
            qf[nt][kk] = *reinterpret_cast<const bf16x8*>(
                Qg + (size_t)(nt * 16 + l15) * 64 + kk * 32 + quad * 8);

    bf16x8 kreg[2], vreg[2];
    for (int i = 0; i < 2; ++i) {
        int v = tid + i * 256;
        kreg[i] = *reinterpret_cast<const bf16x8*>(Kg + (size_t)(v >> 3) * 64 + (v & 7) * 8);
        vreg[i] = *reinterpret_cast<const bf16x8*>(Vg + (size_t)(v >> 3) * 1024 + (v & 7) * 8);
    }

    f32x4 O[4][4];   // [ct][nt]: partial O^T, c=ct*16+quad*4+r, q=nt*16+l15
    for (int ct = 0; ct < 4; ++ct)
        for (int nt = 0; nt < 4; ++nt)
            O[ct][nt] = f32x4{0.f, 0.f, 0.f, 0.f};
    float lsum[4] = {0.f, 0.f, 0.f, 0.f};

    for (int st = 0; st < 16; ++st) {
        __syncthreads();
        for (int i = 0; i < 2; ++i) {
            int v = tid + i * 256;
            *reinterpret_cast<bf16x8*>(sK + (v >> 3) * 72 + (v & 7) * 8) = kreg[i];
            *reinterpret_cast<bf16x8*>(sV + (v >> 3) * 72 + (v & 7) * 8) = vreg[i];
        }
        __syncthreads();
        if (st < 15) {
            int s0n = (st + 1) * 64;
            for (int i = 0; i < 2; ++i) {
                int v = tid + i * 256;
                kreg[i] = *reinterpret_cast<const bf16x8*>(Kg + (size_t)(s0n + (v >> 3)) * 64 + (v & 7) * 8);
                vreg[i] = *reinterpret_cast<const bf16x8*>(Vg + (size_t)(v >> 3) * 1024 + s0n + (v & 7) * 8);
            }
        }

        // ---- S^T = K_w . Q^T : wave's 16 s rows x 64 q ----
        f32x4 S[4];
        for (int nt = 0; nt < 4; ++nt) S[nt] = f32x4{0.f, 0.f, 0.f, 0.f};
        for (int kk = 0; kk < 2; ++kk) {
            bf16x8 kf = *reinterpret_cast<const bf16x8*>(sK + (w * 16 + l15) * 72 + kk * 32 + quad * 8);
            for (int nt = 0; nt < 4; ++nt)
                S[nt] = __builtin_amdgcn_mfma_f32_16x16x32_bf16(kf, qf[nt][kk], S[nt], 0, 0, 0);
        }

        // ---- exp in-register; pack as K=16 operands (k=quad*4+r) ----
        bf16x4 pf[4];
        for (int nt = 0; nt < 4; ++nt)
            for (int r = 0; r < 4; ++r) {
                float p = exp2f(S[nt][r] * K2);
                lsum[nt] += p;
                pf[nt][r] = (bf16_t)p;
            }

        // ---- O^T += V.P^T over wave's 16 s (vf reused across nt) ----
        for (int ct = 0; ct < 4; ++ct) {
            bf16x4 vf = *reinterpret_cast<const bf16x4*>(sV + (ct * 16 + l15) * 72 + w * 16 + quad * 4);
            for (int nt = 0; nt < 4; ++nt)
                O[ct][nt] = mfma16_bf16(vf, pf[nt], O[ct][nt]);
        }
    }

    // lsum[nt]: lane's partial over its 4 r (all tiles) for q=nt*16+l15.
    // Sum across the 4 quads -> every lane holds wave-total per q.
    for (int nt = 0; nt < 4; ++nt) {
        lsum[nt] += __shfl_xor(lsum[nt], 16);
        lsum[nt] += __shfl_xor(lsum[nt], 32);
    }

    __syncthreads();   // done reading sK/sV; reuse as reduction scratch
    if (quad == 0)
        for (int nt = 0; nt < 4; ++nt)
            sL[w * 64 + nt * 16 + l15] = lsum[nt];
    for (int ct = 0; ct < 4; ++ct)
        for (int nt = 0; nt < 4; ++nt) {
            bf16x4 o4;
            for (int r = 0; r < 4; ++r) o4[r] = (bf16_t)O[ct][nt][r];
            *reinterpret_cast<bf16x4*>(
                sO + ((size_t)w * 64 + nt * 16 + l15) * 72 + ct * 16 + quad * 4) = o4;
        }
    __syncthreads();

    // final: thread -> q = tid>>2, c-chunk = (tid&3)*16; sum 4 wave-partials
    int q = tid >> 2, ch = tid & 3;
    float linv = 1.f / (sL[q] + sL[64 + q] + sL[128 + q] + sL[192 + q]);
    float acc[16];
    for (int e = 0; e < 16; ++e) acc[e] = 0.f;
    for (int ww = 0; ww < 4; ++ww) {
        const bf16_t* src = sO + ((size_t)ww * 64 + q) * 72 + ch * 16;
        bf16x8 a = *reinterpret_cast<const bf16x8*>(src);
        bf16x8 b = *reinterpret_cast<const bf16x8*>(src + 8);
        for (int e = 0; e < 8; ++e) { acc[e] += (float)a[e]; acc[8 + e] += (float)b[e]; }
    }
    int bb = bh >> 3, h = bh & 7;
    int t = qt * 64 + q;
    bf16_t* orow = net_t + ((size_t)bb * T_DIM + t) * C_DIM + h * 64 + ch * 16;
    bf16x8 o1, o2;
    for (int e = 0; e < 8; ++e) {
        o1[e] = (bf16_t)(acc[e] * linv);
        o2[e] = (bf16_t)(acc[8 + e] * linv);
    }
    *reinterpret_cast<bf16x8*>(orow) = o1;
    *reinterpret_cast<bf16x8*>(orow + 8) = o2;
}

// ---------------------------------------------------------------------------
// Kernel 4: out GEMM + bias + residual (unchanged).
// ---------------------------------------------------------------------------
__global__ __launch_bounds__(256) void out_gemm_kernel(
    const bf16_t* __restrict__ wob, const float* __restrict__ bo,
    const bf16_t* __restrict__ net_t, const float* __restrict__ x,
    float* __restrict__ out)
{
    __shared__ bf16_t sA[64 * 72];
    __shared__ bf16_t sB[128 * 72];
    int tid = threadIdx.x;
    int w = tid >> 6, lane = tid & 63, quad = lane >> 4, l15 = lane & 15;
    int o0 = blockIdx.x * 64;
    int t0 = blockIdx.y * 128;
    int bb = blockIdx.z;
    const bf16_t* Ab = wob + (size_t)o0 * C_DIM;
    const bf16_t* Bb = net_t + ((size_t)bb * T_DIM + t0) * C_DIM;

    f32x4 acc[2][4];
    for (int mt = 0; mt < 2; ++mt)
        for (int nt = 0; nt < 4; ++nt)
            acc[mt][nt] = f32x4{0.f, 0.f, 0.f, 0.f};
    int mw0 = (w >> 1) * 32;
    int nw0 = (w & 1) * 64;

    for (int k0 = 0; k0 < C_DIM; k0 += 64) {
        for (int i = 0; i < 2; ++i) {
            int v = tid + i * 256;
            int row = v >> 3, c8 = v & 7;
            *reinterpret_cast<bf16x8*>(sA + row * 72 + c8 * 8) =
                *reinterpret_cast<const bf16x8*>(Ab + (size_t)row * C_DIM + k0 + c8 * 8);
        }
        for (int i = 0; i < 4; ++i) {
            int v = tid + i * 256;
            int row = v >> 3, c8 = v & 7;
            *reinterpret_cast<bf16x8*>(sB + row * 72 + c8 * 8) =
                *reinterpret_cast<const bf16x8*>(Bb + (size_t)row * C_DIM + k0 + c8 * 8);
        }
        __syncthreads();
        for (int kk = 0; kk < 2; ++kk) {
            bf16x8 af[2], bfr[4];
            for (int mt = 0; mt < 2; ++mt)
                af[mt] = *reinterpret_cast<const bf16x8*>(sA + (mw0 + mt * 16 + l15) * 72 + kk * 32 + quad * 8);
            for (int nt = 0; nt < 4; ++nt)
                bfr[nt] = *reinterpret_cast<const bf16x8*>(sB + (nw0 + nt * 16 + l15) * 72 + kk * 32 + quad * 8);
            for (int mt = 0; mt < 2; ++mt)
                for (int nt = 0; nt < 4; ++nt)
                    acc[mt][nt] = __builtin_amdgcn_mfma_f32_16x16x32_bf16(af[mt], bfr[nt], acc[mt][nt], 0, 0, 0);
        }
        __syncthreads();
    }

    for (int mt = 0; mt < 2; ++mt)
        for (int nt = 0; nt < 4; ++nt)
            for (int r = 0; r < 4; ++r) {
                int o = o0 + mw0 + mt * 16 + quad * 4 + r;
                int t = t0 + nw0 + nt * 16 + l15;
                size_t idx = ((size_t)bb * C_DIM + o) * T_DIM + t;
                out[idx] = acc[mt][nt][r] + bo[o] + x[idx];
            }
}

// ---------------------------------------------------------------------------
extern "C" void kernel_launch(void* const* d_in, const int* in_sizes, int n_in,
                              void* d_out, int out_size, void* d_ws, size_t ws_size,
                              hipStream_t stream)
{
    const float* x     = (const float*)d_in[0];
    const float* gn_w  = (const float*)d_in[1];
    const float* gn_b  = (const float*)d_in[2];
    const float* qkv_w = (const float*)d_in[3];
    const float* qkv_b = (const float*)d_in[4];
    const float* out_w = (const float*)d_in[5];
    const float* out_b = (const float*)d_in[6];
    float* out = (float*)d_out;

    // ws layout (bf16): n_t 8MB | qkv 24MB | net_t 8MB | wqb 1.5MB | wob 0.5MB
    char* ws = (char*)d_ws;
    bf16_t* n_t   = (bf16_t*)(ws);
    bf16_t* qkv   = (bf16_t*)(ws + 8388608);
    bf16_t* net_t = (bf16_t*)(ws + 33554432);
    bf16_t* wqb   = (bf16_t*)(ws + 41943040);
    bf16_t* wob   = (bf16_t*)(ws + 41943040 + 1572864);

    prep_w<<<dim3(256), 256, 0, stream>>>(qkv_w, out_w, wqb, wob);
    gn_kernel<<<dim3(256), 256, 0, stream>>>(x, gn_w, gn_b, n_t);
    qkv_gemm_kernel<<<dim3(24, 8, 8), 256, 0, stream>>>(wqb, qkv_b, n_t, qkv);
    attn_kernel<<<dim3(64, 16), 256, 0, stream>>>(qkv, net_t);
    out_gemm_kernel<<<dim3(8, 8, 8), 256, 0, stream>>>(wob, out_b, net_t, x, out);
}

// Round 12
// 163.427 us; speedup vs baseline: 1.0620x; 1.0412x over previous
//
#include <hip/hip_runtime.h>
#include <hip/hip_bf16.h>

typedef __bf16 bf16_t;
typedef __bf16 bf16x8 __attribute__((ext_vector_type(8)));
typedef __bf16 bf16x4 __attribute__((ext_vector_type(4)));
typedef short  s16x4  __attribute__((ext_vector_type(4)));
typedef float  f32x4  __attribute__((ext_vector_type(4)));

#define B_DIM 8
#define C_DIM 512
#define T_DIM 1024
#define NH 8
#define HD 64

// v_mfma_f32_16x16x16_bf16: A/B = 4 bf16 (k=quad*4+j, m/n=l15), C row=quad*4+r col=l15.
__device__ __forceinline__ f32x4 mfma16_bf16(bf16x4 a, bf16x4 b, f32x4 c) {
    return __builtin_amdgcn_mfma_f32_16x16x16bf16_1k(
        __builtin_bit_cast(s16x4, a), __builtin_bit_cast(s16x4, b), c, 0, 0, 0);
}

// ---------------------------------------------------------------------------
// Kernel 1a: GN stats (blocks 0..255) + weight fp32->bf16 prep (blocks 256..511).
// stats[(b*32+g)*2] = mean, [..+1] = rstd.
// ---------------------------------------------------------------------------
__global__ __launch_bounds__(256) void gn_stats_prep(const float* __restrict__ x,
                                                     const float* __restrict__ w1,
                                                     const float* __restrict__ w2,
                                                     float* __restrict__ stats,
                                                     bf16_t* __restrict__ o1,
                                                     bf16_t* __restrict__ o2)
{
    int tid = threadIdx.x;
    int bx = blockIdx.x;
    if (bx >= 256) {
        int gt = (bx - 256) * 256 + tid;
        for (int p = 0; p < 4; ++p) {
            int q = gt + p * 65536;
            const f32x4* src;
            bf16x4* dst;
            int qq;
            if (q < 196608) { src = (const f32x4*)w1; dst = (bf16x4*)o1; qq = q; }
            else            { src = (const f32x4*)w2; dst = (bf16x4*)o2; qq = q - 196608; }
            f32x4 f = src[qq];
            bf16x4 h;
            for (int j = 0; j < 4; ++j) h[j] = (bf16_t)f[j];
            dst[qq] = h;
        }
        return;
    }

    __shared__ float sred[8];
    int bb = bx >> 5;
    int g  = bx & 31;
    const f32x4* xg4 = reinterpret_cast<const f32x4*>(x + (size_t)(bb * C_DIM + g * 16) * T_DIM);

    float s = 0.f, sq = 0.f;
    for (int i = 0; i < 16; ++i) {
        f32x4 f = xg4[tid + i * 256];
        for (int j = 0; j < 4; ++j) { s += f[j]; sq += f[j] * f[j]; }
    }
    for (int off = 1; off < 64; off <<= 1) {
        s  += __shfl_xor(s, off);
        sq += __shfl_xor(sq, off);
    }
    int wv = tid >> 6;
    if ((tid & 63) == 0) { sred[wv * 2] = s; sred[wv * 2 + 1] = sq; }
    __syncthreads();
    if (tid == 0) {
        s  = sred[0] + sred[2] + sred[4] + sred[6];
        sq = sred[1] + sred[3] + sred[5] + sred[7];
        float mean = s * (1.f / 16384.f);
        float var  = sq * (1.f / 16384.f) - mean * mean;
        stats[(bb * 32 + g) * 2]     = mean;
        stats[(bb * 32 + g) * 2 + 1] = rsqrtf(var + 1e-5f);
    }
}

// ---------------------------------------------------------------------------
// Kernel 1b: GN apply + transpose.  Block = (b, 32 t-rows).  x read hits L3
// (just touched by stats pass).  LDS transpose (pad 536: 16B-aligned rows,
// conflict-light).  n_t written as fully-contiguous 1KB rows (no partial
// cache lines -- the old gn's 32B-granule scatter was the write hog).
// ---------------------------------------------------------------------------
__global__ __launch_bounds__(256) void gn_apply(const float* __restrict__ x,
                                                const float* __restrict__ gw,
                                                const float* __restrict__ gb,
                                                const float* __restrict__ stats,
                                                bf16_t* __restrict__ n_t)
{
    __shared__ bf16_t sY[32 * 536];
    __shared__ float aArr[512], bArr[512];
    int tid = threadIdx.x;
    int t0 = blockIdx.x * 32;
    int bb = blockIdx.y;

    for (int i = 0; i < 2; ++i) {
        int c = tid + i * 256;
        int g = c >> 4;
        float mean = stats[(bb * 32 + g) * 2];
        float rs   = stats[(bb * 32 + g) * 2 + 1];
        float a = gw[c] * rs;
        aArr[c] = a;
        bArr[c] = gb[c] - mean * a;
    }
    __syncthreads();

    for (int i = 0; i < 16; ++i) {
        int v = tid + i * 256;        // 0..4095 : c = v>>3, t-quad = v&7
        int c = v >> 3, tq = v & 7;
        f32x4 f = *reinterpret_cast<const f32x4*>(
            x + ((size_t)(bb * C_DIM + c) * T_DIM + t0 + tq * 4));
        float a = aArr[c], b = bArr[c];
        for (int j = 0; j < 4; ++j)
            sY[(tq * 4 + j) * 536 + c] = (bf16_t)(f[j] * a + b);
    }
    __syncthreads();

    for (int i = 0; i < 8; ++i) {
        int v = tid + i * 256;        // 0..2047 : t = v>>6, 16B chunk = v&63
        int t = v >> 6, c8 = v & 63;
        bf16x8 d = *reinterpret_cast<const bf16x8*>(sY + t * 536 + c8 * 8);
        *reinterpret_cast<bf16x8*>(
            n_t + ((size_t)bb * T_DIM + t0 + t) * C_DIM + c8 * 8) = d;
    }
}

// ---------------------------------------------------------------------------
// Kernel 2: QKV GEMM (round-9 form: 64x128 tile, grid (24,8,8)).
// ---------------------------------------------------------------------------
__global__ __launch_bounds__(256) void qkv_gemm_kernel(
    const bf16_t* __restrict__ wqb, const float* __restrict__ bq,
    const bf16_t* __restrict__ n_t, bf16_t* __restrict__ qkv)
{
    __shared__ bf16_t sA[64 * 72];
    __shared__ bf16_t sB[128 * 72];
    int tid = threadIdx.x;
    int w = tid >> 6, lane = tid & 63, quad = lane >> 4, l15 = lane & 15;
    int bx = blockIdx.x;          // 0..23  (= h*3 + type)
    int t0 = blockIdx.y * 128;
    int bb = blockIdx.z;
    int o0 = bx * 64;
    const bf16_t* Ab = wqb + (size_t)o0 * C_DIM;
    const bf16_t* Bb = n_t + ((size_t)bb * T_DIM + t0) * C_DIM;

    f32x4 acc[2][4];
    for (int mt = 0; mt < 2; ++mt)
        for (int nt = 0; nt < 4; ++nt)
            acc[mt][nt] = f32x4{0.f, 0.f, 0.f, 0.f};
    int mw0 = (w >> 1) * 32;
    int nw0 = (w & 1) * 64;

    for (int k0 = 0; k0 < C_DIM; k0 += 64) {
        for (int i = 0; i < 2; ++i) {
            int v = tid + i * 256;
            int row = v >> 3, c8 = v & 7;
            *reinterpret_cast<bf16x8*>(sA + row * 72 + c8 * 8) =
                *reinterpret_cast<const bf16x8*>(Ab + (size_t)row * C_DIM + k0 + c8 * 8);
        }
        for (int i = 0; i < 4; ++i) {
            int v = tid + i * 256;
            int row = v >> 3, c8 = v & 7;
            *reinterpret_cast<bf16x8*>(sB + row * 72 + c8 * 8) =
                *reinterpret_cast<const bf16x8*>(Bb + (size_t)row * C_DIM + k0 + c8 * 8);
        }
        __syncthreads();
        for (int kk = 0; kk < 2; ++kk) {
            bf16x8 af[2], bfr[4];
            for (int mt = 0; mt < 2; ++mt)
                af[mt] = *reinterpret_cast<const bf16x8*>(sA + (mw0 + mt * 16 + l15) * 72 + kk * 32 + quad * 8);
            for (int nt = 0; nt < 4; ++nt)
                bfr[nt] = *reinterpret_cast<const bf16x8*>(sB + (nw0 + nt * 16 + l15) * 72 + kk * 32 + quad * 8);
            for (int mt = 0; mt < 2; ++mt)
                for (int nt = 0; nt < 4; ++nt)
                    acc[mt][nt] = __builtin_amdgcn_mfma_f32_16x16x32_bf16(af[mt], bfr[nt], acc[mt][nt], 0, 0, 0);
        }
        __syncthreads();
    }

    int h = bx / 3, type = bx % 3;
    size_t base = ((size_t)(bb * NH + h) * 3 + type) * (64 * 1024);

    if (type < 2) {
        for (int mt = 0; mt < 2; ++mt)
            for (int nt = 0; nt < 4; ++nt)
                for (int r = 0; r < 4; ++r) {
                    int mw = mw0 + mt * 16 + quad * 4 + r;
                    int tl = nw0 + nt * 16 + l15;
                    float v = acc[mt][nt][r] + bq[o0 + mw];
                    sB[tl * 72 + mw] = (bf16_t)v;
                }
        __syncthreads();
        for (int i = 0; i < 4; ++i) {
            int v = tid + i * 256;
            int tl = v >> 3, c8 = v & 7;
            bf16x8 d = *reinterpret_cast<const bf16x8*>(sB + tl * 72 + c8 * 8);
            *reinterpret_cast<bf16x8*>(qkv + base + (size_t)(t0 + tl) * 64 + c8 * 8) = d;
        }
    } else {
        for (int mt = 0; mt < 2; ++mt)
            for (int nt = 0; nt < 4; ++nt)
                for (int r = 0; r < 4; ++r) {
                    int mw = mw0 + mt * 16 + quad * 4 + r;
                    int tl = nw0 + nt * 16 + l15;
                    float v = acc[mt][nt][r] + bq[o0 + mw];
                    sB[mw * 136 + tl] = (bf16_t)v;
                }
        __syncthreads();
        for (int i = 0; i < 4; ++i) {
            int v = tid + i * 256;
            int cc = v >> 4, t8 = (v & 15) * 8;
            bf16x8 d = *reinterpret_cast<const bf16x8*>(sB + cc * 136 + t8);
            *reinterpret_cast<bf16x8*>(qkv + base + (size_t)cc * 1024 + t0 + t8) = d;
        }
    }
}

// ---------------------------------------------------------------------------
// Kernel 3: flash attention (exact round-9 kernel: 44.2 us known-good).
// ---------------------------------------------------------------------------
__global__ __launch_bounds__(256, 6) void attn_kernel(const bf16_t* __restrict__ qkv,
                                                      bf16_t* __restrict__ net_t)
{
    __shared__ bf16_t sK[64 * 72];
    __shared__ bf16_t sV[64 * 72];      // (c=64 rows, s=64 cols)
    int tid = threadIdx.x;
    int w = tid >> 6, lane = tid & 63, quad = lane >> 4, l15 = lane & 15;
    int bh = blockIdx.x;
    int qt = blockIdx.y;
    size_t qb = (size_t)bh * 3 * 65536;
    const bf16_t* Qg = qkv + qb + (size_t)qt * 4096;
    const bf16_t* Kg = qkv + qb + 65536;
    const bf16_t* Vg = qkv + qb + 2 * 65536;
    const float K2 = 0.125f * 1.44269504088896f;   // scale^2 * log2(e)

    bf16x8 qf[2];
    for (int kk = 0; kk < 2; ++kk)
        qf[kk] = *reinterpret_cast<const bf16x8*>(Qg + (size_t)(w * 16 + l15) * 64 + kk * 32 + quad * 8);

    bf16x8 kreg[2], vreg[2];
    for (int i = 0; i < 2; ++i) {
        int v = tid + i * 256;
        kreg[i] = *reinterpret_cast<const bf16x8*>(Kg + (size_t)(v >> 3) * 64 + (v & 7) * 8);
        vreg[i] = *reinterpret_cast<const bf16x8*>(Vg + (size_t)(v >> 3) * 1024 + (v & 7) * 8);
    }

    f32x4 O[4];   // O^T: [ct] rows c=ct*16+quad*4+r, col t=l15
    for (int i = 0; i < 4; ++i) O[i] = f32x4{0.f, 0.f, 0.f, 0.f};
    float lsum = 0.f;

    for (int st = 0; st < 16; ++st) {
        __syncthreads();
        for (int i = 0; i < 2; ++i) {
            int v = tid + i * 256;
            *reinterpret_cast<bf16x8*>(sK + (v >> 3) * 72 + (v & 7) * 8) = kreg[i];
            *reinterpret_cast<bf16x8*>(sV + (v >> 3) * 72 + (v & 7) * 8) = vreg[i];
        }
        __syncthreads();
        if (st < 15) {
            int s0n = (st + 1) * 64;
            for (int i = 0; i < 2; ++i) {
                int v = tid + i * 256;
                kreg[i] = *reinterpret_cast<const bf16x8*>(Kg + (size_t)(s0n + (v >> 3)) * 64 + (v & 7) * 8);
                vreg[i] = *reinterpret_cast<const bf16x8*>(Vg + (size_t)(v >> 3) * 1024 + s0n + (v & 7) * 8);
            }
        }

        for (int mt = 0; mt < 4; ++mt) {
            f32x4 S = f32x4{0.f, 0.f, 0.f, 0.f};
            for (int kk = 0; kk < 2; ++kk) {
                bf16x8 kf = *reinterpret_cast<const bf16x8*>(sK + (mt * 16 + l15) * 72 + kk * 32 + quad * 8);
                S = __builtin_amdgcn_mfma_f32_16x16x32_bf16(kf, qf[kk], S, 0, 0, 0);
            }
            bf16x4 pf;
            for (int r = 0; r < 4; ++r) {
                float p = exp2f(S[r] * K2);
                lsum += p;
                pf[r] = (bf16_t)p;
            }
            for (int ct = 0; ct < 4; ++ct) {
                bf16x4 vf = *reinterpret_cast<const bf16x4*>(sV + (ct * 16 + l15) * 72 + mt * 16 + quad * 4);
                O[ct] = mfma16_bf16(vf, pf, O[ct]);
            }
        }
    }

    lsum += __shfl_xor(lsum, 16);
    lsum += __shfl_xor(lsum, 32);
    float inv = 1.f / lsum;

    int bb = bh >> 3, h = bh & 7;
    int t = qt * 64 + w * 16 + l15;
    bf16_t* orow = net_t + ((size_t)bb * T_DIM + t) * C_DIM + h * 64;
    for (int ct = 0; ct < 4; ++ct) {
        bf16x4 o4;
        for (int r = 0; r < 4; ++r) o4[r] = (bf16_t)(O[ct][r] * inv);
        *reinterpret_cast<bf16x4*>(orow + ct * 16 + quad * 4) = o4;
    }
}

// ---------------------------------------------------------------------------
// Kernel 4: out GEMM + bias + residual (unchanged).
// ---------------------------------------------------------------------------
__global__ __launch_bounds__(256) void out_gemm_kernel(
    const bf16_t* __restrict__ wob, const float* __restrict__ bo,
    const bf16_t* __restrict__ net_t, const float* __restrict__ x,
    float* __restrict__ out)
{
    __shared__ bf16_t sA[64 * 72];
    __shared__ bf16_t sB[128 * 72];
    int tid = threadIdx.x;
    int w = tid >> 6, lane = tid & 63, quad = lane >> 4, l15 = lane & 15;
    int o0 = blockIdx.x * 64;
    int t0 = blockIdx.y * 128;
    int bb = blockIdx.z;
    const bf16_t* Ab = wob + (size_t)o0 * C_DIM;
    const bf16_t* Bb = net_t + ((size_t)bb * T_DIM + t0) * C_DIM;

    f32x4 acc[2][4];
    for (int mt = 0; mt < 2; ++mt)
        for (int nt = 0; nt < 4; ++nt)
            acc[mt][nt] = f32x4{0.f, 0.f, 0.f, 0.f};
    int mw0 = (w >> 1) * 32;
    int nw0 = (w & 1) * 64;

    for (int k0 = 0; k0 < C_DIM; k0 += 64) {
        for (int i = 0; i < 2; ++i) {
            int v = tid + i * 256;
            int row = v >> 3, c8 = v & 7;
            *reinterpret_cast<bf16x8*>(sA + row * 72 + c8 * 8) =
                *reinterpret_cast<const bf16x8*>(Ab + (size_t)row * C_DIM + k0 + c8 * 8);
        }
        for (int i = 0; i < 4; ++i) {
            int v = tid + i * 256;
            int row = v >> 3, c8 = v & 7;
            *reinterpret_cast<bf16x8*>(sB + row * 72 + c8 * 8) =
                *reinterpret_cast<const bf16x8*>(Bb + (size_t)row * C_DIM + k0 + c8 * 8);
        }
        __syncthreads();
        for (int kk = 0; kk < 2; ++kk) {
            bf16x8 af[2], bfr[4];
            for (int mt = 0; mt < 2; ++mt)
                af[mt] = *reinterpret_cast<const bf16x8*>(sA + (mw0 + mt * 16 + l15) * 72 + kk * 32 + quad * 8);
            for (int nt = 0; nt < 4; ++nt)
                bfr[nt] = *reinterpret_cast<const bf16x8*>(sB + (nw0 + nt * 16 + l15) * 72 + kk * 32 + quad * 8);
            for (int mt = 0; mt < 2; ++mt)
                for (int nt = 0; nt < 4; ++nt)
                    acc[mt][nt] = __builtin_amdgcn_mfma_f32_16x16x32_bf16(af[mt], bfr[nt], acc[mt][nt], 0, 0, 0);
        }
        __syncthreads();
    }

    for (int mt = 0; mt < 2; ++mt)
        for (int nt = 0; nt < 4; ++nt)
            for (int r = 0; r < 4; ++r) {
                int o = o0 + mw0 + mt * 16 + quad * 4 + r;
                int t = t0 + nw0 + nt * 16 + l15;
                size_t idx = ((size_t)bb * C_DIM + o) * T_DIM + t;
                out[idx] = acc[mt][nt][r] + bo[o] + x[idx];
            }
}

// ---------------------------------------------------------------------------
extern "C" void kernel_launch(void* const* d_in, const int* in_sizes, int n_in,
                              void* d_out, int out_size, void* d_ws, size_t ws_size,
                              hipStream_t stream)
{
    const float* x     = (const float*)d_in[0];
    const float* gn_w  = (const float*)d_in[1];
    const float* gn_b  = (const float*)d_in[2];
    const float* qkv_w = (const float*)d_in[3];
    const float* qkv_b = (const float*)d_in[4];
    const float* out_w = (const float*)d_in[5];
    const float* out_b = (const float*)d_in[6];
    float* out = (float*)d_out;

    // ws layout (bf16): n_t 8MB | qkv 24MB | net_t 8MB | wqb 1.5MB | wob 0.5MB | stats 2KB
    char* ws = (char*)d_ws;
    bf16_t* n_t   = (bf16_t*)(ws);
    bf16_t* qkv   = (bf16_t*)(ws + 8388608);
    bf16_t* net_t = (bf16_t*)(ws + 33554432);
    bf16_t* wqb   = (bf16_t*)(ws + 41943040);
    bf16_t* wob   = (bf16_t*)(ws + 41943040 + 1572864);
    float*  stats = (float*)(ws + 41943040 + 1572864 + 524288);

    gn_stats_prep<<<dim3(512), 256, 0, stream>>>(x, qkv_w, out_w, stats, wqb, wob);
    gn_apply<<<dim3(32, 8), 256, 0, stream>>>(x, gn_w, gn_b, stats, n_t);
    qkv_gemm_kernel<<<dim3(24, 8, 8), 256, 0, stream>>>(wqb, qkv_b, n_t, qkv);
    attn_kernel<<<dim3(64, 16), 256, 0, stream>>>(qkv, net_t);
    out_gemm_kernel<<<dim3(8, 8, 8), 256, 0, stream>>>(wob, out_b, net_t, x, out);
}